// Round 13
// baseline (473.961 us; speedup 1.0000x reference)
//
#include <hip/hip_runtime.h>

// GCN: N=100000, E=1600000, widths 128 -> 16 -> 64 -> 128 -> 1
// Round 13: R11 base (411us) + XCD-sharded gather64, node-per-lane.
// R10 retry with the instruction-bloat fixed: wave = 64 nodes (one per lane),
// each lane serially walks its CSR segment accumulating an 8-ch strip from
// the shard slab Cb[grp][node][8] (3.2 MB, resident in XCD grp's L2 via the
// blockIdx%8 round-robin). No shuffle reduction; direct stores.
// Pipeline: hist -> scan(+dinv) -> [fill ∥ gemm1] -> gather16(r1)
//           -> g16gemm2(r2, blocked) -> gather64s -> head.

#define NN 100000
#define NE 1600000
#define NB ((NN + 255) / 256)   // 391 blocks for scans

__device__ __forceinline__ float rdl_f(float v, int l) {
    return __int_as_float(__builtin_amdgcn_readlane(__float_as_int(v), l));
}

// ---------------- histogram + rank ----------------
__global__ void hist_rank_k(const int* __restrict__ dst, int* __restrict__ ideg,
                            int* __restrict__ rank, int e) {
    int i = blockIdx.x * blockDim.x + threadIdx.x;
    if (i < e) rank[i] = atomicAdd(&ideg[dst[i]], 1);
}

// ---------------- scan pass 1 (+ fused dinv) ----------------
__global__ void scan_reduce_k(const int* __restrict__ ideg, int* __restrict__ bsum,
                              float* __restrict__ dinv, int n) {
    __shared__ int s[256];
    int i = blockIdx.x * 256 + threadIdx.x;
    int v = (i < n) ? ideg[i] : 0;
    if (i < n) dinv[i] = rsqrtf((float)v + 1.0f);  // +1 self loop
    s[threadIdx.x] = v;
    __syncthreads();
    for (int off = 128; off > 0; off >>= 1) {
        if (threadIdx.x < off) s[threadIdx.x] += s[threadIdx.x + off];
        __syncthreads();
    }
    if (threadIdx.x == 0) bsum[blockIdx.x] = s[0];
}

__global__ __launch_bounds__(512) void scan_partials_k(const int* __restrict__ bsum,
                                                       int* __restrict__ bofs, int nb) {
    __shared__ int s[512];
    int t = threadIdx.x;
    int v = (t < nb) ? bsum[t] : 0;
    s[t] = v;
    __syncthreads();
    for (int off = 1; off < 512; off <<= 1) {
        int a = (t >= off) ? s[t - off] : 0;
        __syncthreads();
        s[t] += a;
        __syncthreads();
    }
    if (t < nb) bofs[t] = s[t] - v;  // exclusive
}

__global__ void scan_final_k(const int* __restrict__ ideg, const int* __restrict__ bofs,
                             int* __restrict__ rowptr, int n, int e) {
    __shared__ int s[256];
    int i = blockIdx.x * 256 + threadIdx.x;
    int t = threadIdx.x;
    int v = (i < n) ? ideg[i] : 0;
    s[t] = v;
    __syncthreads();
    for (int off = 1; off < 256; off <<= 1) {
        int a = (t >= off) ? s[t - off] : 0;
        __syncthreads();
        s[t] += a;
        __syncthreads();
    }
    int excl = s[t] - v + bofs[blockIdx.x];
    if (i < n) rowptr[i] = excl;
    if (i == 0) rowptr[n] = e;
}

// ---------------- fused: CSR fill (blocks < fillBlocks) + gemm1 (rest) ----------------
// gemm1: A = dinv * (x @ W1), K=128, M=16.
__global__ __launch_bounds__(256) void fill_gemm1_k(const int* __restrict__ src,
                                                    const int* __restrict__ dst,
                                                    const int* __restrict__ rank,
                                                    const int* __restrict__ rowptr,
                                                    int* __restrict__ csr_src,
                                                    const float* __restrict__ x,
                                                    const float* __restrict__ W1,
                                                    const float* __restrict__ dinv,
                                                    float* __restrict__ A,
                                                    int e, int n, int fillBlocks) {
    __shared__ float sW[128 * 16];
    __shared__ float sIn[16][132];           // +4 pad
    if ((int)blockIdx.x < fillBlocks) {
        int i = blockIdx.x * 256 + threadIdx.x;
        if (i < e) csr_src[rowptr[dst[i]] + rank[i]] = src[i];
        return;
    }
    const int bid = blockIdx.x - fillBlocks;
    const int tid = threadIdx.x;
    for (int i = tid; i < 128 * 16; i += 256) sW[i] = W1[i];
    const int row0 = bid * 16;
    const float4* in4 = (const float4*)x;
    for (int i = tid; i < 16 * 32; i += 256) {
        int r = i >> 5, kv = i & 31;
        int g = row0 + r;
        float4 v = make_float4(0.f, 0.f, 0.f, 0.f);
        if (g < n) v = in4[(long)g * 32 + kv];
        ((float4*)&sIn[r][0])[kv] = v;
    }
    __syncthreads();
    const int r = tid >> 4, m = tid & 15;
    const int g = row0 + r;
    if (g < n) {
        float acc = 0.0f;
#pragma unroll
        for (int k = 0; k < 128; ++k) acc += sIn[r][k] * sW[k * 16 + m];
        A[(long)g * 16 + m] = acc * dinv[g];
    }
}

// ---------------- pull-gather, 16 ch (weight-free) ----------------
template<bool BIAS_RELU, bool OUT_SCALE>
__global__ __launch_bounds__(256) void gather16_k(const int* __restrict__ rowptr,
                                                  const int* __restrict__ csr_src,
                                                  const float* __restrict__ dinv,
                                                  const float* __restrict__ hs,
                                                  const float* __restrict__ bias,
                                                  float* __restrict__ outp, int n) {
    const int g = (blockIdx.x * 256 + threadIdx.x) >> 6;
    if (g >= n) return;
    const int lane = threadIdx.x & 63;
    const int q = lane & 3;                 // float4 index within 16-ch row
    const int sub = lane >> 2;              // edge subgroup 0..15
    const float dg = dinv[g];
    const int beg = rowptr[g], end = rowptr[g + 1];
    const float4* h4 = (const float4*)hs;
    float4 acc = make_float4(0.f, 0.f, 0.f, 0.f);
    if (sub == 0) acc = h4[(long)g * 4 + q];  // self term
    for (int j0 = beg; j0 < end; j0 += 16) {
        int idx = j0 + sub;
        if (idx < end) {
            const int s = csr_src[idx];
            const float4 v = h4[(long)s * 4 + q];
            acc.x += v.x; acc.y += v.y; acc.z += v.z; acc.w += v.w;
        }
    }
#pragma unroll
    for (int m = 4; m <= 32; m <<= 1) {
        acc.x += __shfl_xor(acc.x, m, 64);
        acc.y += __shfl_xor(acc.y, m, 64);
        acc.z += __shfl_xor(acc.z, m, 64);
        acc.w += __shfl_xor(acc.w, m, 64);
    }
    if (sub == 0) {
        float4 v = make_float4(acc.x * dg, acc.y * dg, acc.z * dg, acc.w * dg);
        if (BIAS_RELU) {
            const float4 b = ((const float4*)bias)[q];
            v.x = fmaxf(v.x + b.x, 0.0f);
            v.y = fmaxf(v.y + b.y, 0.0f);
            v.z = fmaxf(v.z + b.z, 0.0f);
            v.w = fmaxf(v.w + b.w, 0.0f);
        }
        if (OUT_SCALE) { v.x *= dg; v.y *= dg; v.z *= dg; v.w *= dg; }
        ((float4*)outp)[(long)g * 4 + q] = v;
    }
}

// ---------------- fused gather16 + gemm2, GROUP-BLOCKED output ----------------
// Cb[grp][node][8ch], grp = lane>>3: slab stride n*8 floats (3.2 MB).
__global__ __launch_bounds__(256) void g16gemm2_k(const int* __restrict__ rowptr,
                                                  const int* __restrict__ csr_src,
                                                  const float* __restrict__ dinv,
                                                  const float* __restrict__ hs,
                                                  const float* __restrict__ W2,
                                                  const float* __restrict__ b2,
                                                  float* __restrict__ outp, int n) {
    const int lane = threadIdx.x & 63;
    const int wid = blockIdx.x * 4 + (threadIdx.x >> 6);
    const int nWaves = gridDim.x * 4;
    float w2[16];
#pragma unroll
    for (int k = 0; k < 16; ++k) w2[k] = W2[k * 64 + lane];
    const float bm = b2[lane];
    const int q = lane & 3;
    const int sub = lane >> 2;
    const long slab = (long)n * 8;
    float* outg = outp + (long)(lane >> 3) * slab + (lane & 7);
    const float4* h4 = (const float4*)hs;
    for (int g = wid; g < n; g += nWaves) {
        const float dg = dinv[g];
        const int beg = rowptr[g], end = rowptr[g + 1];
        float4 acc = make_float4(0.f, 0.f, 0.f, 0.f);
        if (sub == 0) acc = h4[(long)g * 4 + q];  // self term
        for (int j0 = beg; j0 < end; j0 += 16) {
            int idx = j0 + sub;
            if (idx < end) {
                const int s = csr_src[idx];
                const float4 v = h4[(long)s * 4 + q];
                acc.x += v.x; acc.y += v.y; acc.z += v.z; acc.w += v.w;
            }
        }
#pragma unroll
        for (int m = 4; m <= 32; m <<= 1) {
            acc.x += __shfl_xor(acc.x, m, 64);
            acc.y += __shfl_xor(acc.y, m, 64);
            acc.z += __shfl_xor(acc.z, m, 64);
            acc.w += __shfl_xor(acc.w, m, 64);
        }
        float t = 0.0f;
#pragma unroll
        for (int ql = 0; ql < 4; ++ql) {
            t = fmaf(rdl_f(acc.x, ql), w2[4 * ql + 0], t);
            t = fmaf(rdl_f(acc.y, ql), w2[4 * ql + 1], t);
            t = fmaf(rdl_f(acc.z, ql), w2[4 * ql + 2], t);
            t = fmaf(rdl_f(acc.w, ql), w2[4 * ql + 3], t);
        }
        float r = fmaxf(fmaf(dg, t, bm), 0.0f);   // dg*(sum)@W2 + b2, relu
        outg[(long)g * 8] = r * dg;                // pre-scaled, blocked layout
    }
}

// ---------------- XCD-sharded 64-ch gather, NODE PER LANE ----------------
// shard = blockIdx&7 (round-robins onto XCD shard). Each lane owns one node:
// serially walks its CSR segment, accumulating the node's 8-ch strip from the
// shard's 3.2 MB slab (L2-resident). No reduction tree. Output row-major.
__global__ __launch_bounds__(256) void gather64s_k(const int* __restrict__ rowptr,
                                                   const int* __restrict__ csr_src,
                                                   const float* __restrict__ dinv,
                                                   const float* __restrict__ Cb,
                                                   float* __restrict__ outp, int n) {
    const int shard = blockIdx.x & 7;
    const int g = (blockIdx.x >> 3) * 256 + threadIdx.x;
    if (g >= n) return;
    const float4* s4 = (const float4*)(Cb + (long)shard * ((long)n * 8));
    float4 a0 = s4[(long)g * 2];            // self term (pre-scaled)
    float4 a1 = s4[(long)g * 2 + 1];
    const int beg = rowptr[g], end = rowptr[g + 1];
    int j = beg;
    for (; j + 2 <= end; j += 2) {
        const int sA = csr_src[j];
        const int sB = csr_src[j + 1];
        const float4 vA0 = s4[(long)sA * 2], vA1 = s4[(long)sA * 2 + 1];
        const float4 vB0 = s4[(long)sB * 2], vB1 = s4[(long)sB * 2 + 1];
        a0.x += vA0.x + vB0.x; a0.y += vA0.y + vB0.y;
        a0.z += vA0.z + vB0.z; a0.w += vA0.w + vB0.w;
        a1.x += vA1.x + vB1.x; a1.y += vA1.y + vB1.y;
        a1.z += vA1.z + vB1.z; a1.w += vA1.w + vB1.w;
    }
    if (j < end) {
        const int sA = csr_src[j];
        const float4 vA0 = s4[(long)sA * 2], vA1 = s4[(long)sA * 2 + 1];
        a0.x += vA0.x; a0.y += vA0.y; a0.z += vA0.z; a0.w += vA0.w;
        a1.x += vA1.x; a1.y += vA1.y; a1.z += vA1.z; a1.w += vA1.w;
    }
    const float dg = dinv[g];
    float4* o4 = (float4*)(outp + (long)g * 64 + shard * 8);
    o4[0] = make_float4(a0.x * dg, a0.y * dg, a0.z * dg, a0.w * dg);
    o4[1] = make_float4(a1.x * dg, a1.y * dg, a1.z * dg, a1.w * dg);
}

// ---------------- zero-LDS head (R11): W3 in VGPRs, readlane broadcast ----------------
__global__ __launch_bounds__(256) void head_k(const float* __restrict__ aggS2,
                                              const float* __restrict__ W3,
                                              const float* __restrict__ b3,
                                              const float* __restrict__ Wfc,
                                              const float* __restrict__ bfc,
                                              float* __restrict__ out, int n) {
    const int lane = threadIdx.x & 63;
    const int wid = blockIdx.x * 4 + (threadIdx.x >> 6);
    const int nWaves = gridDim.x * 4;
    float w0[64], w1[64];
#pragma unroll
    for (int k = 0; k < 64; ++k) {
        w0[k] = W3[k * 128 + lane];
        w1[k] = W3[k * 128 + lane + 64];
    }
    const float bm0 = b3[lane], bm1 = b3[lane + 64];
    const float wf0 = Wfc[lane], wf1 = Wfc[lane + 64];
    const float bb = bfc[0];
    for (int g0 = wid * 4; g0 < n; g0 += nWaves * 4) {
        const float* base = aggS2 + (long)g0 * 64 + lane;
        const float rv0 = base[0];
        const float rv1 = base[64];
        const float rv2 = base[128];
        const float rv3 = base[192];
        float a00 = 0.f, a01 = 0.f, a10 = 0.f, a11 = 0.f;
        float a20 = 0.f, a21 = 0.f, a30 = 0.f, a31 = 0.f;
#pragma unroll
        for (int k = 0; k < 64; ++k) {
            const float x0 = rdl_f(rv0, k);
            const float x1 = rdl_f(rv1, k);
            const float x2 = rdl_f(rv2, k);
            const float x3 = rdl_f(rv3, k);
            a00 = fmaf(x0, w0[k], a00); a01 = fmaf(x0, w1[k], a01);
            a10 = fmaf(x1, w0[k], a10); a11 = fmaf(x1, w1[k], a11);
            a20 = fmaf(x2, w0[k], a20); a21 = fmaf(x2, w1[k], a21);
            a30 = fmaf(x3, w0[k], a30); a31 = fmaf(x3, w1[k], a31);
        }
        float v0 = fmaxf(a00 + bm0, 0.f) * wf0 + fmaxf(a01 + bm1, 0.f) * wf1;
        float v1 = fmaxf(a10 + bm0, 0.f) * wf0 + fmaxf(a11 + bm1, 0.f) * wf1;
        float v2 = fmaxf(a20 + bm0, 0.f) * wf0 + fmaxf(a21 + bm1, 0.f) * wf1;
        float v3 = fmaxf(a30 + bm0, 0.f) * wf0 + fmaxf(a31 + bm1, 0.f) * wf1;
#pragma unroll
        for (int off = 32; off > 0; off >>= 1) {
            v0 += __shfl_down(v0, off, 64);
            v1 += __shfl_down(v1, off, 64);
            v2 += __shfl_down(v2, off, 64);
            v3 += __shfl_down(v3, off, 64);
        }
        if (lane == 0)
            ((float4*)out)[g0 >> 2] = make_float4(v0 + bb, v1 + bb, v2 + bb, v3 + bb);
    }
}

extern "C" void kernel_launch(void* const* d_in, const int* in_sizes, int n_in,
                              void* d_out, int out_size, void* d_ws, size_t ws_size,
                              hipStream_t stream) {
    const float* x    = (const float*)d_in[0];
    const int*   ei   = (const int*)d_in[1];       // [2,E]: src = ei, dst = ei+E
    const float* W1   = (const float*)d_in[2];
    const float* b1   = (const float*)d_in[3];
    const float* W2   = (const float*)d_in[4];
    const float* b2   = (const float*)d_in[5];
    const float* W3   = (const float*)d_in[6];
    const float* b3   = (const float*)d_in[7];
    const float* Wfc  = (const float*)d_in[8];
    const float* bfc  = (const float*)d_in[9];
    float* out = (float*)d_out;

    const int* src = ei;
    const int* dst = ei + NE;

    // workspace layout (4-byte elems; arena offsets 16B-aligned):
    // dinv[N] | ideg[N] | rowptr[N+8] | bsum[512] | bofs[512] | rank[E]
    // | csr_src[E+64] | A[64N] | B[64N] | C[64N]
    float* dinv    = (float*)d_ws;
    int*   ideg    = (int*)(dinv + NN);
    int*   rowptr  = ideg + NN;
    int*   bsum    = rowptr + NN + 8;
    int*   bofs    = bsum + 512;
    int*   rank    = bofs + 512;
    int*   csr_src = rank + NE;
    float* A       = (float*)(csr_src + NE + 64);
    float* B       = A + (long)NN * 64;
    float* C       = B + (long)NN * 64;

    const int T = 256;

    // ---- CSR + norm build ----
    hipMemsetAsync(ideg, 0, NN * sizeof(int), stream);
    hist_rank_k<<<(NE + T - 1) / T, T, 0, stream>>>(dst, ideg, rank, NE);
    scan_reduce_k<<<NB, T, 0, stream>>>(ideg, bsum, dinv, NN);
    scan_partials_k<<<1, 512, 0, stream>>>(bsum, bofs, NB);
    scan_final_k<<<NB, T, 0, stream>>>(ideg, bofs, rowptr, NN, NE);

    // ---- [fill ∥ gemm1: A = dinv * x@W1] ----
    const int fillBlocks = (NE + T - 1) / T;           // 6250
    const int gemmBlocks = (NN + 15) / 16;             // 6250
    fill_gemm1_k<<<fillBlocks + gemmBlocks, T, 0, stream>>>(
        src, dst, rank, rowptr, csr_src, x, W1, dinv, A, NE, NN, fillBlocks);

    // ---- B = dinv * relu(dg*(sum A) + b1)  (pre-scaled r1, 16ch) ----
    gather16_k<true, true><<<(NN + 3) / 4, T, 0, stream>>>(rowptr, csr_src, dinv, A, b1, B, NN);
    // ---- C(blocked) = dinv * relu(dg*(sum B)@W2 + b2)  (pre-scaled r2, 64ch) ----
    g16gemm2_k<<<3072, T, 0, stream>>>(rowptr, csr_src, dinv, B, W2, b2, C, NN);
    // ---- A(64ch, row-major) = dg * sum C  (XCD-sharded, node-per-lane) ----
    gather64s_k<<<NB * 8, T, 0, stream>>>(rowptr, csr_src, dinv, C, A, NN);
    // ---- head: out = relu(A@W3 + b3).Wfc + bfc ----
    head_k<<<2048, T, 0, stream>>>(A, W3, b3, Wfc, bfc, out, NN);
}

// Round 14
// 414.663 us; speedup vs baseline: 1.1430x; 1.1430x over previous
//
#include <hip/hip_runtime.h>

// GCN: N=100000, E=1600000, widths 128 -> 16 -> 64 -> 128 -> 1
// Round 14: R11 base (best measured, 411us) + two isolated tweaks:
//  - hist_rank: 4 edges/thread (int4 dst load, 4 independent atomics in
//    flight, int4 rank store) — attacks atomic latency, the hidden ~80us.
//  - head: 8 nodes/wave (R12 version) — halves per-wave W3 preload traffic.
// gather64 kept at the R9/R11 structural floor (sharding failed twice:
// R10 instruction bloat, R13 miss traffic returned).
// Pipeline: hist -> scan(+dinv) -> [fill ∥ gemm1] -> gather16(r1)
//           -> g16gemm2(r2) -> gather64 -> head.

#define NN 100000
#define NE 1600000
#define NB ((NN + 255) / 256)   // 391 blocks for scans

__device__ __forceinline__ float rdl_f(float v, int l) {
    return __int_as_float(__builtin_amdgcn_readlane(__float_as_int(v), l));
}

// ---------------- histogram + rank, 4 edges/thread ----------------
// NE % 4 == 0. int4 loads keep coalescing; 4 independent atomics per thread.
__global__ void hist_rank_k(const int* __restrict__ dst, int* __restrict__ ideg,
                            int* __restrict__ rank, int e4) {
    int i = blockIdx.x * blockDim.x + threadIdx.x;
    if (i < e4) {
        int4 d = ((const int4*)dst)[i];
        int4 r;
        r.x = atomicAdd(&ideg[d.x], 1);
        r.y = atomicAdd(&ideg[d.y], 1);
        r.z = atomicAdd(&ideg[d.z], 1);
        r.w = atomicAdd(&ideg[d.w], 1);
        ((int4*)rank)[i] = r;
    }
}

// ---------------- scan pass 1 (+ fused dinv) ----------------
__global__ void scan_reduce_k(const int* __restrict__ ideg, int* __restrict__ bsum,
                              float* __restrict__ dinv, int n) {
    __shared__ int s[256];
    int i = blockIdx.x * 256 + threadIdx.x;
    int v = (i < n) ? ideg[i] : 0;
    if (i < n) dinv[i] = rsqrtf((float)v + 1.0f);  // +1 self loop
    s[threadIdx.x] = v;
    __syncthreads();
    for (int off = 128; off > 0; off >>= 1) {
        if (threadIdx.x < off) s[threadIdx.x] += s[threadIdx.x + off];
        __syncthreads();
    }
    if (threadIdx.x == 0) bsum[blockIdx.x] = s[0];
}

__global__ __launch_bounds__(512) void scan_partials_k(const int* __restrict__ bsum,
                                                       int* __restrict__ bofs, int nb) {
    __shared__ int s[512];
    int t = threadIdx.x;
    int v = (t < nb) ? bsum[t] : 0;
    s[t] = v;
    __syncthreads();
    for (int off = 1; off < 512; off <<= 1) {
        int a = (t >= off) ? s[t - off] : 0;
        __syncthreads();
        s[t] += a;
        __syncthreads();
    }
    if (t < nb) bofs[t] = s[t] - v;  // exclusive
}

__global__ void scan_final_k(const int* __restrict__ ideg, const int* __restrict__ bofs,
                             int* __restrict__ rowptr, int n, int e) {
    __shared__ int s[256];
    int i = blockIdx.x * 256 + threadIdx.x;
    int t = threadIdx.x;
    int v = (i < n) ? ideg[i] : 0;
    s[t] = v;
    __syncthreads();
    for (int off = 1; off < 256; off <<= 1) {
        int a = (t >= off) ? s[t - off] : 0;
        __syncthreads();
        s[t] += a;
        __syncthreads();
    }
    int excl = s[t] - v + bofs[blockIdx.x];
    if (i < n) rowptr[i] = excl;
    if (i == 0) rowptr[n] = e;
}

// ---------------- fused: CSR fill (blocks < fillBlocks) + gemm1 (rest) ----------------
// gemm1: A = dinv * (x @ W1), K=128, M=16.
__global__ __launch_bounds__(256) void fill_gemm1_k(const int* __restrict__ src,
                                                    const int* __restrict__ dst,
                                                    const int* __restrict__ rank,
                                                    const int* __restrict__ rowptr,
                                                    int* __restrict__ csr_src,
                                                    const float* __restrict__ x,
                                                    const float* __restrict__ W1,
                                                    const float* __restrict__ dinv,
                                                    float* __restrict__ A,
                                                    int e, int n, int fillBlocks) {
    __shared__ float sW[128 * 16];
    __shared__ float sIn[16][132];           // +4 pad
    if ((int)blockIdx.x < fillBlocks) {
        int i = blockIdx.x * 256 + threadIdx.x;
        if (i < e) csr_src[rowptr[dst[i]] + rank[i]] = src[i];
        return;
    }
    const int bid = blockIdx.x - fillBlocks;
    const int tid = threadIdx.x;
    for (int i = tid; i < 128 * 16; i += 256) sW[i] = W1[i];
    const int row0 = bid * 16;
    const float4* in4 = (const float4*)x;
    for (int i = tid; i < 16 * 32; i += 256) {
        int r = i >> 5, kv = i & 31;
        int g = row0 + r;
        float4 v = make_float4(0.f, 0.f, 0.f, 0.f);
        if (g < n) v = in4[(long)g * 32 + kv];
        ((float4*)&sIn[r][0])[kv] = v;
    }
    __syncthreads();
    const int r = tid >> 4, m = tid & 15;
    const int g = row0 + r;
    if (g < n) {
        float acc = 0.0f;
#pragma unroll
        for (int k = 0; k < 128; ++k) acc += sIn[r][k] * sW[k * 16 + m];
        A[(long)g * 16 + m] = acc * dinv[g];
    }
}

// ---------------- pull-gather, 16 ch (weight-free) ----------------
template<bool BIAS_RELU, bool OUT_SCALE>
__global__ __launch_bounds__(256) void gather16_k(const int* __restrict__ rowptr,
                                                  const int* __restrict__ csr_src,
                                                  const float* __restrict__ dinv,
                                                  const float* __restrict__ hs,
                                                  const float* __restrict__ bias,
                                                  float* __restrict__ outp, int n) {
    const int g = (blockIdx.x * 256 + threadIdx.x) >> 6;
    if (g >= n) return;
    const int lane = threadIdx.x & 63;
    const int q = lane & 3;                 // float4 index within 16-ch row
    const int sub = lane >> 2;              // edge subgroup 0..15
    const float dg = dinv[g];
    const int beg = rowptr[g], end = rowptr[g + 1];
    const float4* h4 = (const float4*)hs;
    float4 acc = make_float4(0.f, 0.f, 0.f, 0.f);
    if (sub == 0) acc = h4[(long)g * 4 + q];  // self term
    for (int j0 = beg; j0 < end; j0 += 16) {
        int idx = j0 + sub;
        if (idx < end) {
            const int s = csr_src[idx];
            const float4 v = h4[(long)s * 4 + q];
            acc.x += v.x; acc.y += v.y; acc.z += v.z; acc.w += v.w;
        }
    }
#pragma unroll
    for (int m = 4; m <= 32; m <<= 1) {
        acc.x += __shfl_xor(acc.x, m, 64);
        acc.y += __shfl_xor(acc.y, m, 64);
        acc.z += __shfl_xor(acc.z, m, 64);
        acc.w += __shfl_xor(acc.w, m, 64);
    }
    if (sub == 0) {
        float4 v = make_float4(acc.x * dg, acc.y * dg, acc.z * dg, acc.w * dg);
        if (BIAS_RELU) {
            const float4 b = ((const float4*)bias)[q];
            v.x = fmaxf(v.x + b.x, 0.0f);
            v.y = fmaxf(v.y + b.y, 0.0f);
            v.z = fmaxf(v.z + b.z, 0.0f);
            v.w = fmaxf(v.w + b.w, 0.0f);
        }
        if (OUT_SCALE) { v.x *= dg; v.y *= dg; v.z *= dg; v.w *= dg; }
        ((float4*)outp)[(long)g * 4 + q] = v;
    }
}

// ---------------- fused gather16 + gemm2: C = dinv*relu(dg*(sum Bs)@W2 + b2) ----------------
__global__ __launch_bounds__(256) void g16gemm2_k(const int* __restrict__ rowptr,
                                                  const int* __restrict__ csr_src,
                                                  const float* __restrict__ dinv,
                                                  const float* __restrict__ hs,
                                                  const float* __restrict__ W2,
                                                  const float* __restrict__ b2,
                                                  float* __restrict__ outp, int n) {
    const int lane = threadIdx.x & 63;
    const int wid = blockIdx.x * 4 + (threadIdx.x >> 6);
    const int nWaves = gridDim.x * 4;
    float w2[16];
#pragma unroll
    for (int k = 0; k < 16; ++k) w2[k] = W2[k * 64 + lane];
    const float bm = b2[lane];
    const int q = lane & 3;
    const int sub = lane >> 2;
    const float4* h4 = (const float4*)hs;
    for (int g = wid; g < n; g += nWaves) {
        const float dg = dinv[g];
        const int beg = rowptr[g], end = rowptr[g + 1];
        float4 acc = make_float4(0.f, 0.f, 0.f, 0.f);
        if (sub == 0) acc = h4[(long)g * 4 + q];  // self term
        for (int j0 = beg; j0 < end; j0 += 16) {
            int idx = j0 + sub;
            if (idx < end) {
                const int s = csr_src[idx];
                const float4 v = h4[(long)s * 4 + q];
                acc.x += v.x; acc.y += v.y; acc.z += v.z; acc.w += v.w;
            }
        }
#pragma unroll
        for (int m = 4; m <= 32; m <<= 1) {
            acc.x += __shfl_xor(acc.x, m, 64);
            acc.y += __shfl_xor(acc.y, m, 64);
            acc.z += __shfl_xor(acc.z, m, 64);
            acc.w += __shfl_xor(acc.w, m, 64);
        }
        float t = 0.0f;
#pragma unroll
        for (int ql = 0; ql < 4; ++ql) {
            t = fmaf(rdl_f(acc.x, ql), w2[4 * ql + 0], t);
            t = fmaf(rdl_f(acc.y, ql), w2[4 * ql + 1], t);
            t = fmaf(rdl_f(acc.z, ql), w2[4 * ql + 2], t);
            t = fmaf(rdl_f(acc.w, ql), w2[4 * ql + 3], t);
        }
        float r = fmaxf(fmaf(dg, t, bm), 0.0f);   // dg*(sum)@W2 + b2, relu
        outp[(long)g * 64 + lane] = r * dg;        // pre-scaled for next gather
    }
}

// ---------------- pull-gather, 64 ch ----------------
__global__ __launch_bounds__(256) void gather64_k(const int* __restrict__ rowptr,
                                                  const int* __restrict__ csr_src,
                                                  const float* __restrict__ dinv,
                                                  const float* __restrict__ hs,
                                                  float* __restrict__ outp, int n) {
    const int g = (blockIdx.x * 256 + threadIdx.x) >> 6;
    if (g >= n) return;
    const int lane = threadIdx.x & 63;
    const int q = lane & 15;                // float4 index within 64-ch row
    const int sub = lane >> 4;              // edge subgroup 0..3
    const float dg = dinv[g];
    const int beg = rowptr[g], end = rowptr[g + 1];
    const float4* h4 = (const float4*)hs;
    float4 acc = make_float4(0.f, 0.f, 0.f, 0.f);
    if (sub == 0) acc = h4[(long)g * 16 + q];  // self term
    int j0 = beg;
    for (; j0 + 8 <= end; j0 += 8) {
        const int s0 = csr_src[j0 + sub];
        const int s1 = csr_src[j0 + 4 + sub];
        const float4 v0 = h4[(long)s0 * 16 + q];
        const float4 v1 = h4[(long)s1 * 16 + q];
        acc.x += v0.x + v1.x; acc.y += v0.y + v1.y;
        acc.z += v0.z + v1.z; acc.w += v0.w + v1.w;
    }
    for (; j0 < end; j0 += 4) {
        int idx = j0 + sub;
        if (idx < end) {
            const int s = csr_src[idx];
            const float4 v = h4[(long)s * 16 + q];
            acc.x += v.x; acc.y += v.y; acc.z += v.z; acc.w += v.w;
        }
    }
#pragma unroll
    for (int m = 16; m <= 32; m <<= 1) {
        acc.x += __shfl_xor(acc.x, m, 64);
        acc.y += __shfl_xor(acc.y, m, 64);
        acc.z += __shfl_xor(acc.z, m, 64);
        acc.w += __shfl_xor(acc.w, m, 64);
    }
    if (sub == 0) {
        ((float4*)outp)[(long)g * 16 + q] =
            make_float4(acc.x * dg, acc.y * dg, acc.z * dg, acc.w * dg);
    }
}

// ---------------- zero-LDS head, 8 nodes per wave ----------------
// N % 8 == 0. W3 cols in 128 VGPRs; readlane broadcasts; 16 FMA chains.
__global__ __launch_bounds__(256) void head_k(const float* __restrict__ aggS2,
                                              const float* __restrict__ W3,
                                              const float* __restrict__ b3,
                                              const float* __restrict__ Wfc,
                                              const float* __restrict__ bfc,
                                              float* __restrict__ out, int n) {
    const int lane = threadIdx.x & 63;
    const int wid = blockIdx.x * 4 + (threadIdx.x >> 6);
    const int nWaves = gridDim.x * 4;
    float w0[64], w1[64];
#pragma unroll
    for (int k = 0; k < 64; ++k) {
        w0[k] = W3[k * 128 + lane];
        w1[k] = W3[k * 128 + lane + 64];
    }
    const float bm0 = b3[lane], bm1 = b3[lane + 64];
    const float wf0 = Wfc[lane], wf1 = Wfc[lane + 64];
    const float bb = bfc[0];
    for (int g0 = wid * 8; g0 < n; g0 += nWaves * 8) {
        const float* base = aggS2 + (long)g0 * 64 + lane;
        float rv[8];
#pragma unroll
        for (int i = 0; i < 8; ++i) rv[i] = base[i * 64];
        float a0[8], a1[8];
#pragma unroll
        for (int i = 0; i < 8; ++i) { a0[i] = 0.f; a1[i] = 0.f; }
#pragma unroll
        for (int k = 0; k < 64; ++k) {
            const float wa = w0[k], wb = w1[k];
#pragma unroll
            for (int i = 0; i < 8; ++i) {
                const float xk = rdl_f(rv[i], k);
                a0[i] = fmaf(xk, wa, a0[i]);
                a1[i] = fmaf(xk, wb, a1[i]);
            }
        }
        float v[8];
#pragma unroll
        for (int i = 0; i < 8; ++i)
            v[i] = fmaxf(a0[i] + bm0, 0.f) * wf0 + fmaxf(a1[i] + bm1, 0.f) * wf1;
#pragma unroll
        for (int off = 32; off > 0; off >>= 1) {
#pragma unroll
            for (int i = 0; i < 8; ++i) v[i] += __shfl_down(v[i], off, 64);
        }
        if (lane == 0) {
            ((float4*)out)[(g0 >> 2) + 0] = make_float4(v[0] + bb, v[1] + bb, v[2] + bb, v[3] + bb);
            ((float4*)out)[(g0 >> 2) + 1] = make_float4(v[4] + bb, v[5] + bb, v[6] + bb, v[7] + bb);
        }
    }
}

extern "C" void kernel_launch(void* const* d_in, const int* in_sizes, int n_in,
                              void* d_out, int out_size, void* d_ws, size_t ws_size,
                              hipStream_t stream) {
    const float* x    = (const float*)d_in[0];
    const int*   ei   = (const int*)d_in[1];       // [2,E]: src = ei, dst = ei+E
    const float* W1   = (const float*)d_in[2];
    const float* b1   = (const float*)d_in[3];
    const float* W2   = (const float*)d_in[4];
    const float* b2   = (const float*)d_in[5];
    const float* W3   = (const float*)d_in[6];
    const float* b3   = (const float*)d_in[7];
    const float* Wfc  = (const float*)d_in[8];
    const float* bfc  = (const float*)d_in[9];
    float* out = (float*)d_out;

    const int* src = ei;
    const int* dst = ei + NE;

    // workspace layout (4-byte elems; arena offsets 16B-aligned):
    // dinv[N] | ideg[N] | rowptr[N+8] | bsum[512] | bofs[512] | rank[E]
    // | csr_src[E+64] | A[64N] | B[64N] | C[64N]
    float* dinv    = (float*)d_ws;
    int*   ideg    = (int*)(dinv + NN);
    int*   rowptr  = ideg + NN;
    int*   bsum    = rowptr + NN + 8;
    int*   bofs    = bsum + 512;
    int*   rank    = bofs + 512;
    int*   csr_src = rank + NE;
    float* A       = (float*)(csr_src + NE + 64);
    float* B       = A + (long)NN * 64;
    float* C       = B + (long)NN * 64;

    const int T = 256;

    // ---- CSR + norm build ----
    hipMemsetAsync(ideg, 0, NN * sizeof(int), stream);
    const int e4 = NE / 4;                              // 400000
    hist_rank_k<<<(e4 + T - 1) / T, T, 0, stream>>>(dst, ideg, rank, e4);
    scan_reduce_k<<<NB, T, 0, stream>>>(ideg, bsum, dinv, NN);
    scan_partials_k<<<1, 512, 0, stream>>>(bsum, bofs, NB);
    scan_final_k<<<NB, T, 0, stream>>>(ideg, bofs, rowptr, NN, NE);

    // ---- [fill ∥ gemm1: A = dinv * x@W1] ----
    const int fillBlocks = (NE + T - 1) / T;           // 6250
    const int gemmBlocks = (NN + 15) / 16;             // 6250
    fill_gemm1_k<<<fillBlocks + gemmBlocks, T, 0, stream>>>(
        src, dst, rank, rowptr, csr_src, x, W1, dinv, A, NE, NN, fillBlocks);

    // ---- B = dinv * relu(dg*(sum A) + b1)  (pre-scaled r1, 16ch) ----
    gather16_k<true, true><<<(NN + 3) / 4, T, 0, stream>>>(rowptr, csr_src, dinv, A, b1, B, NN);
    // ---- C = dinv * relu(dg*(sum B)@W2 + b2)  (pre-scaled r2, 64ch) ----
    g16gemm2_k<<<3072, T, 0, stream>>>(rowptr, csr_src, dinv, B, W2, b2, C, NN);
    // ---- A(64ch) = dg * sum C  (aggS2) ----
    gather64_k<<<(NN + 3) / 4, T, 0, stream>>>(rowptr, csr_src, dinv, C, A, NN);
    // ---- head: out = relu(A@W3 + b3).Wfc + bfc ----
    head_k<<<1024, T, 0, stream>>>(A, W3, b3, Wfc, bfc, out, NN);
}